// Round 1
// baseline (923.820 us; speedup 1.0000x reference)
//
#include <hip/hip_runtime.h>
#include <cstdint>
#include <cstddef>

#define B_SZ 16384
#define NNUM 13
#define NFIELDS 26
#define VOCAB 100000
#define K_FM 64
#define DEEPIN 1677
#define DEEPPAD 1696   // 53 * 32
#define H1 1024
#define H2 512
#define H3 256

typedef _Float16 f16;
typedef _Float16 f16x8 __attribute__((ext_vector_type(8)));
typedef float f32x4 __attribute__((ext_vector_type(4)));

// ---------------- gather + FM second order + first order ----------------
// one wave per sample; lane = k (K_FM == 64 == wave size)
__global__ __launch_bounds__(256) void gather_fm(
    const float* __restrict__ x_num, const int* __restrict__ x_cat,
    const float* __restrict__ bias, const float* __restrict__ w_num,
    const float* __restrict__ lin_cat, const float* __restrict__ v_num,
    const float* __restrict__ v_cat, f16* __restrict__ deep_in,
    float* __restrict__ out)
{
    const int lane = threadIdx.x & 63;
    const int b = blockIdx.x * 4 + (threadIdx.x >> 6);

    float xn = (lane < NNUM) ? x_num[b * NNUM + lane] : 0.f;
    int idx = (lane < NFIELDS) ? x_cat[b * NFIELDS + lane] : 0;

    float sum_v = 0.f, sumsq = 0.f;
    const size_t bbase = (size_t)b * DEEPPAD;

#pragma unroll
    for (int f = 0; f < NFIELDS; f++) {
        int id = __shfl(idx, f, 64);
        float val = v_cat[((size_t)f * VOCAB + id) * K_FM + lane];
        sum_v += val; sumsq += val * val;
        deep_in[bbase + NNUM + f * K_FM + lane] = (f16)val;
    }
#pragma unroll
    for (int i = 0; i < NNUM; i++) {
        float xi = __shfl(xn, i, 64);
        float vv = xi * v_num[i * K_FM + lane];
        sum_v += vv; sumsq += vv * vv;
    }
    float part = sum_v * sum_v - sumsq;   // per-k contribution

    float linp = 0.f;
    if (lane < NFIELDS) linp = lin_cat[(size_t)lane * VOCAB + idx];
    if (lane < NNUM)    linp += xn * w_num[lane];

#pragma unroll
    for (int off = 32; off > 0; off >>= 1) {
        part += __shfl_down(part, off, 64);
        linp += __shfl_down(linp, off, 64);
    }

    if (lane < NNUM) deep_in[bbase + lane] = (f16)xn;
    if (lane < DEEPPAD - DEEPIN) deep_in[bbase + DEEPIN + lane] = (f16)0.f; // zero K-pad
    if (lane == 0) out[b] = bias[0] + linp + 0.5f * part;
}

// ---------------- weight transpose + fp16 convert: W[K][N] -> Wt[N][Kp] ----------------
__global__ __launch_bounds__(256) void transpose_w(
    const float* __restrict__ W, f16* __restrict__ Wt, int K, int Kp, int N)
{
    __shared__ float t[32][33];
    const int k0 = blockIdx.x * 32, n0 = blockIdx.y * 32;
    const int tx = threadIdx.x & 31, ty = threadIdx.x >> 5;  // 32 x 8
#pragma unroll
    for (int r = 0; r < 32; r += 8) {
        int k = k0 + ty + r;
        t[ty + r][tx] = (k < K) ? W[(size_t)k * N + n0 + tx] : 0.f;
    }
    __syncthreads();
#pragma unroll
    for (int r = 0; r < 32; r += 8) {
        Wt[(size_t)(n0 + ty + r) * Kp + k0 + tx] = (f16)t[tx][ty + r];
    }
}

// ---------------- GEMM: C[m][n] = relu(sum_k A[m][k]*Bt[n][k] + bias[n]) ----------------
// 128x128 tile, BK=32, 4 waves in 2x2, each wave 64x64 via 4x4 MFMA 16x16x32 tiles.
// Staging via global_load_lds (16B/lane, linear LDS dest); LDS bank-conflict
// swizzle done by pre-swizzling the per-lane GLOBAL source k-chunk:
//   physical k-chunk = logical k-chunk ^ (row bits [2:1])
// so every 16-lane ds_read_b128 fragment covers all 8 16B positions of the
// 128B bank span (2 lanes each -> conflict-free).
__global__ __launch_bounds__(256) void gemm_bt_relu(
    const f16* __restrict__ A, const f16* __restrict__ Bt,
    const float* __restrict__ bias, f16* __restrict__ C,
    int Kp, int N)
{
    __shared__ __align__(16) f16 smem[8192];   // As[128*32] | Bs[128*32]
    const int tid = threadIdx.x;
    const int lane = tid & 63, wv = tid >> 6;
    const int m0 = blockIdx.x * 128, n0 = blockIdx.y * 128;
    const int wm = (wv & 1) * 64, wn = (wv >> 1) * 64;
    const int lrow = lane & 15;

    // ---- staging setup: 16 chunks of 1KB (16 rows x 64B); wave wv owns chunks wv*4..wv*4+3
    const int rsub = lane >> 2;                 // row within a 16-row chunk (4 lanes/row)
    const int swzL = (lane >> 3) & 3;           // row bits [2:1] (row = lane>>2)
    const int lcL  = (lane & 3) ^ swzL;         // logical k-chunk this lane fetches
    const f16* gptr[4];
    f16* lptr[4];
#pragma unroll
    for (int j = 0; j < 4; j++) {
        const int ci = wv * 4 + j;              // 0..15; 0-7 = A, 8-15 = B
        const int rr = (ci & 7) * 16 + rsub;    // tile row 0..127
        gptr[j] = (ci < 8 ? A + (size_t)(m0 + rr) * Kp
                          : Bt + (size_t)(n0 + rr) * Kp) + lcL * 8;
        lptr[j] = smem + ci * 512;              // 512 f16 = 1KB per chunk, linear
    }

    // ---- fragment-read swizzle: physical chunk offset for this lane (row-bits from lrow)
    const int pc8 = ((lane >> 4) ^ ((lrow >> 1) & 3)) * 8;

    f32x4 acc[4][4] = {};

    for (int k0 = 0; k0 < Kp; k0 += 32) {
#pragma unroll
        for (int j = 0; j < 4; j++)
            __builtin_amdgcn_global_load_lds(
                (const __attribute__((address_space(1))) void*)(gptr[j] + k0),
                (__attribute__((address_space(3))) void*)lptr[j], 16, 0, 0);
        __syncthreads();

        f16x8 af[4], bf[4];
#pragma unroll
        for (int mt = 0; mt < 4; mt++)
            af[mt] = *(const f16x8*)&smem[(size_t)(wm + mt * 16 + lrow) * 32 + pc8];
#pragma unroll
        for (int nt = 0; nt < 4; nt++)
            bf[nt] = *(const f16x8*)&smem[4096 + (size_t)(wn + nt * 16 + lrow) * 32 + pc8];
#pragma unroll
        for (int mt = 0; mt < 4; mt++)
#pragma unroll
            for (int nt = 0; nt < 4; nt++)
                acc[mt][nt] = __builtin_amdgcn_mfma_f32_16x16x32_f16(
                    af[mt], bf[nt], acc[mt][nt], 0, 0, 0);
        __syncthreads();
    }

    // epilogue: D row = (lane>>4)*4 + r, col = lane&15 (within each 16x16 tile)
    const int orow = (lane >> 4) * 4, ocol = lane & 15;
#pragma unroll
    for (int mt = 0; mt < 4; mt++) {
#pragma unroll
        for (int r = 0; r < 4; r++) {
            const int m = m0 + wm + mt * 16 + orow + r;
#pragma unroll
            for (int nt = 0; nt < 4; nt++) {
                const int n = n0 + wn + nt * 16 + ocol;
                float v = acc[mt][nt][r] + bias[n];
                v = fmaxf(v, 0.f);
                C[(size_t)m * N + n] = (f16)v;
            }
        }
    }
}

// ---------------- final: out[b] += h3[b,:] . Wo + bo ----------------
__global__ __launch_bounds__(256) void final_out(
    const f16* __restrict__ h3, const float* __restrict__ Wo,
    const float* __restrict__ bo, float* __restrict__ out)
{
    const int lane = threadIdx.x & 63;
    const int b = blockIdx.x * 4 + (threadIdx.x >> 6);
    float s = 0.f;
#pragma unroll
    for (int j = 0; j < 4; j++)
        s += (float)h3[(size_t)b * H3 + lane * 4 + j] * Wo[lane * 4 + j];
#pragma unroll
    for (int off = 32; off > 0; off >>= 1) s += __shfl_down(s, off, 64);
    if (lane == 0) out[b] += s + bo[0];
}

extern "C" void kernel_launch(void* const* d_in, const int* in_sizes, int n_in,
                              void* d_out, int out_size, void* d_ws, size_t ws_size,
                              hipStream_t stream) {
    const float* x_num   = (const float*)d_in[0];
    const int*   x_cat   = (const int*)  d_in[1];
    const float* bias    = (const float*)d_in[2];
    const float* w_num   = (const float*)d_in[3];
    const float* lin_cat = (const float*)d_in[4];
    const float* v_num   = (const float*)d_in[5];
    const float* v_cat   = (const float*)d_in[6];
    const float* W1      = (const float*)d_in[7];
    const float* b1      = (const float*)d_in[8];
    const float* W2      = (const float*)d_in[9];
    const float* b2      = (const float*)d_in[10];
    const float* W3      = (const float*)d_in[11];
    const float* b3      = (const float*)d_in[12];
    const float* Wo      = (const float*)d_in[13];
    const float* bo      = (const float*)d_in[14];
    float* out = (float*)d_out;

    char* ws = (char*)d_ws;
    f16* deep_in = (f16*)ws;  ws += (size_t)B_SZ * DEEPPAD * sizeof(f16);
    f16* h1      = (f16*)ws;  ws += (size_t)B_SZ * H1 * sizeof(f16);
    f16* h2      = (f16*)ws;  ws += (size_t)B_SZ * H2 * sizeof(f16);
    f16* h3      = (f16*)ws;  ws += (size_t)B_SZ * H3 * sizeof(f16);
    f16* W1t     = (f16*)ws;  ws += (size_t)H1 * DEEPPAD * sizeof(f16);
    f16* W2t     = (f16*)ws;  ws += (size_t)H2 * H1 * sizeof(f16);
    f16* W3t     = (f16*)ws;  ws += (size_t)H3 * H2 * sizeof(f16);

    transpose_w<<<dim3(DEEPPAD / 32, H1 / 32), 256, 0, stream>>>(W1, W1t, DEEPIN, DEEPPAD, H1);
    transpose_w<<<dim3(H1 / 32, H2 / 32),      256, 0, stream>>>(W2, W2t, H1, H1, H2);
    transpose_w<<<dim3(H2 / 32, H3 / 32),      256, 0, stream>>>(W3, W3t, H2, H2, H3);

    gather_fm<<<B_SZ / 4, 256, 0, stream>>>(x_num, x_cat, bias, w_num, lin_cat,
                                            v_num, v_cat, deep_in, out);

    gemm_bt_relu<<<dim3(B_SZ / 128, H1 / 128), 256, 0, stream>>>(deep_in, W1t, b1, h1, DEEPPAD, H1);
    gemm_bt_relu<<<dim3(B_SZ / 128, H2 / 128), 256, 0, stream>>>(h1, W2t, b2, h2, H1, H2);
    gemm_bt_relu<<<dim3(B_SZ / 128, H3 / 128), 256, 0, stream>>>(h2, W3t, b3, h3, H2, H3);

    final_out<<<B_SZ / 4, 256, 0, stream>>>(h3, Wo, bo, out);
}

// Round 2
// 916.284 us; speedup vs baseline: 1.0082x; 1.0082x over previous
//
#include <hip/hip_runtime.h>
#include <cstdint>
#include <cstddef>

#define B_SZ 16384
#define NNUM 13
#define NFIELDS 26
#define VOCAB 100000
#define K_FM 64
#define DEEPIN 1677
#define DEEPPAD 1696   // 53 * 32
#define H1 1024
#define H2 512
#define H3 256

typedef _Float16 f16;
typedef _Float16 f16x8 __attribute__((ext_vector_type(8)));
typedef float f32x4 __attribute__((ext_vector_type(4)));

// ---------------- gather + FM second order + first order ----------------
// one wave per sample; lane = k (K_FM == 64 == wave size)
__global__ __launch_bounds__(256) void gather_fm(
    const float* __restrict__ x_num, const int* __restrict__ x_cat,
    const float* __restrict__ bias, const float* __restrict__ w_num,
    const float* __restrict__ lin_cat, const float* __restrict__ v_num,
    const float* __restrict__ v_cat, f16* __restrict__ deep_in,
    const float* __restrict__ bo, float* __restrict__ out)
{
    const int lane = threadIdx.x & 63;
    const int b = blockIdx.x * 4 + (threadIdx.x >> 6);

    float xn = (lane < NNUM) ? x_num[b * NNUM + lane] : 0.f;
    int idx = (lane < NFIELDS) ? x_cat[b * NFIELDS + lane] : 0;

    float sum_v = 0.f, sumsq = 0.f;
    const size_t bbase = (size_t)b * DEEPPAD;

#pragma unroll
    for (int f = 0; f < NFIELDS; f++) {
        int id = __shfl(idx, f, 64);
        float val = v_cat[((size_t)f * VOCAB + id) * K_FM + lane];
        sum_v += val; sumsq += val * val;
        deep_in[bbase + NNUM + f * K_FM + lane] = (f16)val;
    }
#pragma unroll
    for (int i = 0; i < NNUM; i++) {
        float xi = __shfl(xn, i, 64);
        float vv = xi * v_num[i * K_FM + lane];
        sum_v += vv; sumsq += vv * vv;
    }
    float part = sum_v * sum_v - sumsq;   // per-k contribution

    float linp = 0.f;
    if (lane < NFIELDS) linp = lin_cat[(size_t)lane * VOCAB + idx];
    if (lane < NNUM)    linp += xn * w_num[lane];

#pragma unroll
    for (int off = 32; off > 0; off >>= 1) {
        part += __shfl_down(part, off, 64);
        linp += __shfl_down(linp, off, 64);
    }

    if (lane < NNUM) deep_in[bbase + lane] = (f16)xn;
    if (lane < DEEPPAD - DEEPIN) deep_in[bbase + DEEPIN + lane] = (f16)0.f; // zero K-pad
    if (lane == 0) out[b] = bias[0] + bo[0] + linp + 0.5f * part;
}

// ---------------- fused weight transpose + fp16 convert: W[K][N] -> Wt[N][Kp] ----------------
__device__ __forceinline__ void transpose_tile(
    const float* __restrict__ W, f16* __restrict__ Wt,
    int K, int Kp, int N, int bx, int by)
{
    __shared__ float t[32][33];
    const int k0 = bx * 32, n0 = by * 32;
    const int tx = threadIdx.x & 31, ty = threadIdx.x >> 5;  // 32 x 8
#pragma unroll
    for (int r = 0; r < 32; r += 8) {
        int k = k0 + ty + r;
        t[ty + r][tx] = (k < K) ? W[(size_t)k * N + n0 + tx] : 0.f;
    }
    __syncthreads();
#pragma unroll
    for (int r = 0; r < 32; r += 8) {
        Wt[(size_t)(n0 + ty + r) * Kp + k0 + tx] = (f16)t[tx][ty + r];
    }
}

#define NB1 ((DEEPPAD / 32) * (H1 / 32))   // 53*32 = 1696
#define NB2 ((H1 / 32) * (H2 / 32))        // 32*16 = 512
#define NB3 ((H2 / 32) * (H3 / 32))        // 16*8  = 128

__global__ __launch_bounds__(256) void transpose_all(
    const float* __restrict__ W1, f16* __restrict__ W1t,
    const float* __restrict__ W2, f16* __restrict__ W2t,
    const float* __restrict__ W3, f16* __restrict__ W3t)
{
    int bid = blockIdx.x;
    if (bid < NB1) {
        transpose_tile(W1, W1t, DEEPIN, DEEPPAD, H1, bid % (DEEPPAD / 32), bid / (DEEPPAD / 32));
    } else if (bid < NB1 + NB2) {
        bid -= NB1;
        transpose_tile(W2, W2t, H1, H1, H2, bid % (H1 / 32), bid / (H1 / 32));
    } else {
        bid -= NB1 + NB2;
        transpose_tile(W3, W3t, H2, H2, H3, bid % (H2 / 32), bid / (H2 / 32));
    }
}

// ---------------- GEMM: C[m][n] = relu(sum_k A[m][k]*Bt[n][k] + bias[n]) ----------------
// 128x128 tile, BK=32, 4 waves in 2x2, each wave 64x64 via 4x4 MFMA 16x16x32 tiles.
// Staging via global_load_lds (16B/lane, linear LDS dest); bank-conflict swizzle
// done by pre-swizzling the per-lane GLOBAL source k-chunk (phys = log ^ row[2:1]).
// FINAL: instead of storing C, fuse h3 . Wo partial dot, atomicAdd into out.
template<bool FINAL>
__global__ __launch_bounds__(256) void gemm_bt_relu(
    const f16* __restrict__ A, const f16* __restrict__ Bt,
    const float* __restrict__ bias, f16* __restrict__ C,
    int Kp, int N, const float* __restrict__ Wo, float* __restrict__ out)
{
    __shared__ __align__(16) f16 smem[8192];   // As[128*32] | Bs[128*32]
    const int tid = threadIdx.x;
    const int lane = tid & 63, wv = tid >> 6;
    const int m0 = blockIdx.x * 128, n0 = blockIdx.y * 128;
    const int wm = (wv & 1) * 64, wn = (wv >> 1) * 64;
    const int lrow = lane & 15;

    // ---- staging setup: 16 chunks of 1KB (16 rows x 64B); wave wv owns chunks wv*4..wv*4+3
    const int rsub = lane >> 2;                 // row within a 16-row chunk (4 lanes/row)
    const int swzL = (lane >> 3) & 3;           // row bits [2:1] (row = lane>>2)
    const int lcL  = (lane & 3) ^ swzL;         // logical k-chunk this lane fetches
    const f16* gptr[4];
    f16* lptr[4];
#pragma unroll
    for (int j = 0; j < 4; j++) {
        const int ci = wv * 4 + j;              // 0..15; 0-7 = A, 8-15 = B
        const int rr = (ci & 7) * 16 + rsub;    // tile row 0..127
        gptr[j] = (ci < 8 ? A + (size_t)(m0 + rr) * Kp
                          : Bt + (size_t)(n0 + rr) * Kp) + lcL * 8;
        lptr[j] = smem + ci * 512;              // 512 f16 = 1KB per chunk, linear
    }

    // ---- fragment-read swizzle: physical chunk offset for this lane (row-bits from lrow)
    const int pc8 = ((lane >> 4) ^ ((lrow >> 1) & 3)) * 8;

    f32x4 acc[4][4] = {};

    for (int k0 = 0; k0 < Kp; k0 += 32) {
#pragma unroll
        for (int j = 0; j < 4; j++)
            __builtin_amdgcn_global_load_lds(
                (const __attribute__((address_space(1))) void*)(gptr[j] + k0),
                (__attribute__((address_space(3))) void*)lptr[j], 16, 0, 0);
        __syncthreads();

        f16x8 af[4], bf[4];
#pragma unroll
        for (int mt = 0; mt < 4; mt++)
            af[mt] = *(const f16x8*)&smem[(size_t)(wm + mt * 16 + lrow) * 32 + pc8];
#pragma unroll
        for (int nt = 0; nt < 4; nt++)
            bf[nt] = *(const f16x8*)&smem[4096 + (size_t)(wn + nt * 16 + lrow) * 32 + pc8];
#pragma unroll
        for (int mt = 0; mt < 4; mt++)
#pragma unroll
            for (int nt = 0; nt < 4; nt++)
                acc[mt][nt] = __builtin_amdgcn_mfma_f32_16x16x32_f16(
                    af[mt], bf[nt], acc[mt][nt], 0, 0, 0);
        __syncthreads();
    }

    // epilogue: D row = (lane>>4)*4 + r, col = lane&15 (within each 16x16 tile)
    const int orow = (lane >> 4) * 4, ocol = lane & 15;

    if constexpr (FINAL) {
        // h3 row-slice . Wo, reduced across the 16-lane col group, atomicAdd to out
        float wo[4];
#pragma unroll
        for (int nt = 0; nt < 4; nt++) wo[nt] = Wo[n0 + wn + nt * 16 + ocol];
#pragma unroll
        for (int mt = 0; mt < 4; mt++) {
#pragma unroll
            for (int r = 0; r < 4; r++) {
                float s = 0.f;
#pragma unroll
                for (int nt = 0; nt < 4; nt++) {
                    const int n = n0 + wn + nt * 16 + ocol;
                    float v = fmaxf(acc[mt][nt][r] + bias[n], 0.f);
                    s += v * wo[nt];
                }
#pragma unroll
                for (int off = 8; off > 0; off >>= 1)
                    s += __shfl_xor(s, off, 64);
                if (ocol == 0) {
                    const int m = m0 + wm + mt * 16 + orow + r;
                    atomicAdd(&out[m], s);
                }
            }
        }
    } else {
#pragma unroll
        for (int mt = 0; mt < 4; mt++) {
#pragma unroll
            for (int r = 0; r < 4; r++) {
                const int m = m0 + wm + mt * 16 + orow + r;
#pragma unroll
                for (int nt = 0; nt < 4; nt++) {
                    const int n = n0 + wn + nt * 16 + ocol;
                    float v = acc[mt][nt][r] + bias[n];
                    v = fmaxf(v, 0.f);
                    C[(size_t)m * N + n] = (f16)v;
                }
            }
        }
    }
}

extern "C" void kernel_launch(void* const* d_in, const int* in_sizes, int n_in,
                              void* d_out, int out_size, void* d_ws, size_t ws_size,
                              hipStream_t stream) {
    const float* x_num   = (const float*)d_in[0];
    const int*   x_cat   = (const int*)  d_in[1];
    const float* bias    = (const float*)d_in[2];
    const float* w_num   = (const float*)d_in[3];
    const float* lin_cat = (const float*)d_in[4];
    const float* v_num   = (const float*)d_in[5];
    const float* v_cat   = (const float*)d_in[6];
    const float* W1      = (const float*)d_in[7];
    const float* b1      = (const float*)d_in[8];
    const float* W2      = (const float*)d_in[9];
    const float* b2      = (const float*)d_in[10];
    const float* W3      = (const float*)d_in[11];
    const float* b3      = (const float*)d_in[12];
    const float* Wo      = (const float*)d_in[13];
    const float* bo      = (const float*)d_in[14];
    float* out = (float*)d_out;

    char* ws = (char*)d_ws;
    f16* deep_in = (f16*)ws;  ws += (size_t)B_SZ * DEEPPAD * sizeof(f16);
    f16* h1      = (f16*)ws;  ws += (size_t)B_SZ * H1 * sizeof(f16);
    f16* h2      = (f16*)ws;  ws += (size_t)B_SZ * H2 * sizeof(f16);
    f16* W1t     = (f16*)ws;  ws += (size_t)H1 * DEEPPAD * sizeof(f16);
    f16* W2t     = (f16*)ws;  ws += (size_t)H2 * H1 * sizeof(f16);
    f16* W3t     = (f16*)ws;  ws += (size_t)H3 * H2 * sizeof(f16);

    transpose_all<<<NB1 + NB2 + NB3, 256, 0, stream>>>(W1, W1t, W2, W2t, W3, W3t);

    gather_fm<<<B_SZ / 4, 256, 0, stream>>>(x_num, x_cat, bias, w_num, lin_cat,
                                            v_num, v_cat, deep_in, bo, out);

    gemm_bt_relu<false><<<dim3(B_SZ / 128, H1 / 128), 256, 0, stream>>>(
        deep_in, W1t, b1, h1, DEEPPAD, H1, nullptr, nullptr);
    gemm_bt_relu<false><<<dim3(B_SZ / 128, H2 / 128), 256, 0, stream>>>(
        h1, W2t, b2, h2, H1, H2, nullptr, nullptr);
    gemm_bt_relu<true><<<dim3(B_SZ / 128, H3 / 128), 256, 0, stream>>>(
        h2, W3t, b3, nullptr, H2, H3, Wo, out);
}